// Round 1
// baseline (10715.883 us; speedup 1.0000x reference)
//
#include <hip/hip_runtime.h>
#include <math.h>

#define SEQ    128
#define BATCH  32
#define NINP   1024
#define NGATE  4096   // 4*NINP
#define DEPTH  10
#define NPOL   22     // 2*(DEPTH+1)
#define NVOCAB 32000
#define DEC_OFF 131072000ll   // SEQ*BATCH*NVOCAB

__device__ __forceinline__ float sigf(float x){ return 1.0f/(1.0f + expf(-x)); }

// ---------------- init: copy h0, c0, memory0 into working state ----------------
__global__ __launch_bounds__(256) void k_init(const float* __restrict__ h0,
    const float* __restrict__ c0, const float* __restrict__ m0,
    float* __restrict__ h, float* __restrict__ c, float* __restrict__ mem){
  int i = blockIdx.x*256 + threadIdx.x;
  if (i < BATCH*NINP){ h[i] = h0[i]; c[i] = c0[i]; }
  if (i < BATCH*DEPTH*NINP){ mem[i] = m0[i]; }
}

// ---------------- generic f32 GEMM: C[m,n] = sum_k A[m,k]*B[n,k] + bias ----------------
// A rows optionally gathered through Aidx (embedding lookup fused).
// BM=BN=128, BK=16, 256 threads, 8x8 micro-tile.
__global__ __launch_bounds__(256) void k_gemm_abt(
    const float* __restrict__ A, const int* __restrict__ Aidx,
    const float* __restrict__ B, const float* __restrict__ bias0,
    const float* __restrict__ bias1, float* __restrict__ C,
    int K, int ldc){
  __shared__ __align__(16) float As[16][132];
  __shared__ __align__(16) float Bs[16][132];
  const int m1 = blockIdx.y*128, n1 = blockIdx.x*128;
  const int tid = threadIdx.x;
  const int tm = (tid & 15)*8, tn = (tid >> 4)*8;
  float acc[8][8];
  #pragma unroll
  for (int i=0;i<8;i++)
    #pragma unroll
    for (int j=0;j<8;j++) acc[i][j] = 0.f;

  for (int k0=0; k0<K; k0+=16){
    #pragma unroll
    for (int i=0;i<8;i++){
      int l = tid + 256*i;
      int r = l >> 4, kk = l & 15;
      const float* ap = Aidx ? (A + (size_t)Aidx[m1+r]*K) : (A + (size_t)(m1+r)*K);
      As[kk][r] = ap[k0+kk];
      Bs[kk][r] = B[(size_t)(n1+r)*K + k0 + kk];
    }
    __syncthreads();
    #pragma unroll
    for (int kk=0;kk<16;kk++){
      float a[8], bb[8];
      #pragma unroll
      for (int i=0;i<8;i++) a[i] = As[kk][tm+i];
      #pragma unroll
      for (int j=0;j<8;j++) bb[j] = Bs[kk][tn+j];
      #pragma unroll
      for (int i=0;i<8;i++)
        #pragma unroll
        for (int j=0;j<8;j++) acc[i][j] = fmaf(a[i], bb[j], acc[i][j]);
    }
    __syncthreads();
  }
  float bv[8];
  #pragma unroll
  for (int j=0;j<8;j++){
    int n = n1 + tn + j;
    bv[j] = (bias0 ? bias0[n] : 0.f) + (bias1 ? bias1[n] : 0.f);
  }
  #pragma unroll
  for (int i=0;i<8;i++){
    size_t row = (size_t)(m1+tm+i)*ldc + n1 + tn;
    #pragma unroll
    for (int j=0;j<8;j++) C[row+j] = acc[i][j] + bv[j];
  }
}

// ---------------- xp[m,p] = emb(m) . pol_w[p] + pol_b[p] ----------------
__global__ __launch_bounds__(256) void k_xp(const float* __restrict__ enc,
    const int* __restrict__ inputs, const float* __restrict__ pol_w,
    const float* __restrict__ pol_b, float* __restrict__ xp){
  const int m = blockIdx.x;
  const float* x = enc + (size_t)inputs[m]*NINP;
  __shared__ float xs[NINP];
  for (int i=threadIdx.x; i<NINP; i+=256) xs[i] = x[i];
  __syncthreads();
  const int wave = threadIdx.x >> 6, lane = threadIdx.x & 63;
  for (int p = wave; p < NPOL; p += 4){
    const float* w = pol_w + (size_t)p*NINP;
    float s = 0.f;
    for (int k=lane; k<NINP; k+=64) s = fmaf(xs[k], w[k], s);
    #pragma unroll
    for (int off=32; off; off>>=1) s += __shfl_down(s, off);
    if (lane==0) xp[(size_t)m*NPOL + p] = s + pol_b[p];
  }
}

// ---------------- per step, phase 1: gates = xg + h @ w_hh^T ; policy softmax ----------------
// blocks 0..255: gates matmul (16 j-columns each). blocks 256..287: policy for one b.
__global__ __launch_bounds__(256) void k_step1(
    const float* __restrict__ w_hh, const float* __restrict__ h,
    const float* __restrict__ xg, float* __restrict__ gates,
    const float* __restrict__ mem, const float* __restrict__ conv_w,
    const float* __restrict__ conv_b, const float* __restrict__ xp,
    float* __restrict__ pol, int t){
  const int bid = blockIdx.x, tid = threadIdx.x;
  if (bid < 256){
    __shared__ __align__(16) float hl[32][132];
    __shared__ __align__(16) float wl[16][132];
    const int j0 = bid*16;
    const int b = tid >> 3, jj = tid & 7;
    float acc0 = 0.f, acc1 = 0.f;
    for (int k0=0; k0<NINP; k0+=128){
      #pragma unroll
      for (int i=0;i<16;i++){
        int l = tid + 256*i; int r = l>>7, kk = l&127;
        hl[r][kk] = h[r*NINP + k0 + kk];
      }
      #pragma unroll
      for (int i=0;i<8;i++){
        int l = tid + 256*i; int r = l>>7, kk = l&127;
        wl[r][kk] = w_hh[(size_t)(j0+r)*NINP + k0 + kk];
      }
      __syncthreads();
      #pragma unroll 8
      for (int kk=0; kk<128; kk+=4){
        float4 h4 = *(const float4*)&hl[b][kk];
        float4 wa = *(const float4*)&wl[jj][kk];
        float4 wb = *(const float4*)&wl[jj+8][kk];
        acc0 = fmaf(h4.x,wa.x,acc0); acc0 = fmaf(h4.y,wa.y,acc0);
        acc0 = fmaf(h4.z,wa.z,acc0); acc0 = fmaf(h4.w,wa.w,acc0);
        acc1 = fmaf(h4.x,wb.x,acc1); acc1 = fmaf(h4.y,wb.y,acc1);
        acc1 = fmaf(h4.z,wb.z,acc1); acc1 = fmaf(h4.w,wb.w,acc1);
      }
      __syncthreads();
    }
    const size_t m = (size_t)t*BATCH + b;
    gates[b*NGATE + j0 + jj]     = acc0 + xg[m*NGATE + j0 + jj];
    gates[b*NGATE + j0 + jj + 8] = acc1 + xg[m*NGATE + j0 + jj + 8];
  } else {
    const int b = bid - 256;
    __shared__ float logits[NPOL];
    const int wave = tid >> 6, lane = tid & 63;
    for (int p = wave; p < NPOL; p += 4){
      const int o = p/11, tp = p%11;
      float s = 0.f;
      if (tp < DEPTH){
        const float* mr = mem + b*DEPTH*NINP + tp*NINP;
        for (int n=lane; n<NINP; n+=64) s = fmaf(mr[n], conv_w[o*2*NINP + n*2], s);
      }
      if (tp+1 < DEPTH){
        const float* mr = mem + b*DEPTH*NINP + (tp+1)*NINP;
        for (int n=lane; n<NINP; n+=64) s = fmaf(mr[n], conv_w[o*2*NINP + n*2 + 1], s);
      }
      #pragma unroll
      for (int off=32; off; off>>=1) s += __shfl_down(s, off);
      if (lane==0) logits[p] = s + conv_b[o] + xp[((size_t)t*BATCH + b)*NPOL + p];
    }
    __syncthreads();
    if (tid==0){
      float mx = logits[0];
      for (int p=1;p<NPOL;p++) mx = fmaxf(mx, logits[p]);
      float e[NPOL]; float sum = 0.f;
      for (int p=0;p<NPOL;p++){ e[p] = expf(logits[p]-mx); sum += e[p]; }
      float inv = 1.f/sum;
      for (int p=0;p<NPOL;p++) pol[b*NPOL+p] = e[p]*inv;
    }
  }
}

// ---------------- per step, phase 2: LSTM elementwise + stack memory update ----------------
__global__ __launch_bounds__(256) void k_step2(
    const float* __restrict__ gates, const float* __restrict__ pol,
    float* __restrict__ h, float* __restrict__ c, float* __restrict__ mem,
    float* __restrict__ hs, int t){
  const int gid = blockIdx.x*256 + threadIdx.x;   // 0..32767
  const int b = gid >> 10, n = gid & 1023;
  const float ii = gates[b*NGATE + n];
  const float ff = gates[b*NGATE + NINP + n];
  const float gg = gates[b*NGATE + 2*NINP + n];
  const float oo = gates[b*NGATE + 3*NINP + n];
  float cc = sigf(ff)*c[gid] + sigf(ii)*tanhf(gg);
  float hh = sigf(oo)*tanhf(cc);
  c[gid] = cc; h[gid] = hh;
  hs[((size_t)t*BATCH + b)*NINP + n] = hh;

  float p[NPOL];
  #pragma unroll
  for (int k=0;k<NPOL;k++) p[k] = pol[b*NPOL + k];
  float psum = 0.f;
  #pragma unroll
  for (int k=11;k<22;k++) psum += p[k];
  float m[DEPTH];
  #pragma unroll
  for (int j=0;j<DEPTH;j++) m[j] = mem[b*DEPTH*NINP + j*NINP + n];
  float outv[DEPTH];
  {
    float v = psum*hh;
    #pragma unroll
    for (int j=0;j<DEPTH;j++) v = fmaf(p[j], m[j], v);
    outv[0] = v;
  }
  #pragma unroll
  for (int d=1; d<DEPTH; d++){
    float v = 0.f;
    for (int j=d;   j<DEPTH; j++) v = fmaf(p[j-d],    m[j], v);  // stay: p_stay[j-d]
    for (int j=d-1; j<DEPTH; j++) v = fmaf(p[12+j-d], m[j], v);  // push: p_push[j-d+1]
    outv[d] = v;
  }
  #pragma unroll
  for (int d=0; d<DEPTH; d++) mem[b*DEPTH*NINP + d*NINP + n] = outv[d];
}

// ---------------- tail: hT, cT, memT ----------------
__global__ __launch_bounds__(256) void k_tail(const float* __restrict__ h,
    const float* __restrict__ c, const float* __restrict__ mem, float* __restrict__ out){
  int i = blockIdx.x*256 + threadIdx.x;
  float* o = out + DEC_OFF;
  if (i < BATCH*NINP){ o[i] = h[i]; o[BATCH*NINP + i] = c[i]; }
  if (i < BATCH*DEPTH*NINP){ o[2*BATCH*NINP + i] = mem[i]; }
}

extern "C" void kernel_launch(void* const* d_in, const int* in_sizes, int n_in,
                              void* d_out, int out_size, void* d_ws, size_t ws_size,
                              hipStream_t stream){
  (void)in_sizes; (void)n_in; (void)out_size; (void)ws_size;
  const int*   inputs = (const int*)  d_in[0];
  const float* h0     = (const float*)d_in[1];
  const float* c0     = (const float*)d_in[2];
  const float* m0     = (const float*)d_in[3];
  const float* enc    = (const float*)d_in[4];
  const float* dbias  = (const float*)d_in[5];
  const float* w_ih   = (const float*)d_in[6];
  const float* w_hh   = (const float*)d_in[7];
  const float* b_ih   = (const float*)d_in[8];
  const float* b_hh   = (const float*)d_in[9];
  const float* conv_w = (const float*)d_in[10];
  const float* conv_b = (const float*)d_in[11];
  const float* pol_w  = (const float*)d_in[12];
  const float* pol_b  = (const float*)d_in[13];

  float* out = (float*)d_out;
  float* ws  = (float*)d_ws;
  // ws layout (floats): hs 4194304 | gates 131072 | h 32768 | c 32768 | mem 327680 | xp 90112 | pol 704
  float* hs    = ws;
  float* gates = hs    + 4194304;
  float* hbuf  = gates + 131072;
  float* cbuf  = hbuf  + 32768;
  float* mem   = cbuf  + 32768;
  float* xp    = mem   + 327680;
  float* pol   = xp    + 90112;
  // big scratch xg (SEQ*BATCH x 4096 = 16.7M floats) lives in the decoded region of
  // d_out; it is fully consumed by the scan before the decode GEMM overwrites it.
  float* xg    = out;

  k_init<<<1280, 256, 0, stream>>>(h0, c0, m0, hbuf, cbuf, mem);

  // xg[m,j] = emb(m) . w_ih[j] + b_ih[j] + b_hh[j]   (M=4096, N=4096, K=1024)
  dim3 gxg(32, 32);
  k_gemm_abt<<<gxg, 256, 0, stream>>>(enc, inputs, w_ih, b_ih, b_hh, xg, NINP, NGATE);

  k_xp<<<SEQ*BATCH, 256, 0, stream>>>(enc, inputs, pol_w, pol_b, xp);

  for (int t=0; t<SEQ; ++t){
    k_step1<<<288, 256, 0, stream>>>(w_hh, hbuf, xg, gates, mem, conv_w, conv_b, xp, pol, t);
    k_step2<<<128, 256, 0, stream>>>(gates, pol, hbuf, cbuf, mem, hs, t);
  }

  // decoded = hs @ enc^T + dec_bias   (M=4096, N=32000, K=1024)
  dim3 gdec(250, 32);
  k_gemm_abt<<<gdec, 256, 0, stream>>>(hs, nullptr, enc, dbias, nullptr, out, NINP, NVOCAB);

  k_tail<<<1280, 256, 0, stream>>>(hbuf, cbuf, mem, out);
}

// Round 2
// 6410.255 us; speedup vs baseline: 1.6717x; 1.6717x over previous
//
#include <hip/hip_runtime.h>
#include <math.h>

#define SEQ    128
#define BATCH  32
#define NINP   1024
#define NGATE  4096   // 4*NINP
#define DEPTH  10
#define NPOL   22     // 2*(DEPTH+1)
#define NVOCAB 32000
#define DEC_OFF 131072000ll   // SEQ*BATCH*NVOCAB

typedef __attribute__((ext_vector_type(8))) short bf16x8;
typedef __attribute__((ext_vector_type(4))) float f32x4;

__device__ __forceinline__ float sigf(float x){ return 1.0f/(1.0f + expf(-x)); }

__device__ __forceinline__ unsigned short f2bf(float x){
  unsigned int u = __float_as_uint(x);
  unsigned int r = (u + 0x7FFFu + ((u >> 16) & 1u)) >> 16;   // RNE
  return (unsigned short)r;
}

// ---------------- init: copy h0, c0, memory0 into working state ----------------
__global__ __launch_bounds__(256) void k_init(const float* __restrict__ h0,
    const float* __restrict__ c0, const float* __restrict__ m0,
    float* __restrict__ h, float* __restrict__ c, float* __restrict__ mem){
  int i = blockIdx.x*256 + threadIdx.x;
  if (i < BATCH*NINP){ h[i] = h0[i]; c[i] = c0[i]; }
  if (i < BATCH*DEPTH*NINP){ mem[i] = m0[i]; }
}

// ---------------- bf16 MFMA GEMM: C[m,n] = sum_k A[m,k]*B[n,k] + bias ----------------
// A,B are f32 row-major with K-stride (B already transposed: N x K).
// A rows optionally gathered through Aidx. 128x128 tile, BK=32, 4 waves (2x2),
// mfma_f32_16x16x32_bf16, 4x4 fragments per wave. f32->bf16 RNE in staging.
__global__ __launch_bounds__(256) void k_gemm_bf16(
    const float* __restrict__ A, const int* __restrict__ Aidx,
    const float* __restrict__ B, const float* __restrict__ bias0,
    const float* __restrict__ bias1, float* __restrict__ C,
    int K, int ldc){
  __shared__ __align__(16) unsigned short As[128][40];   // pad 32->40: bank-friendly
  __shared__ __align__(16) unsigned short Bs[128][40];
  const int m1 = blockIdx.y*128, n1 = blockIdx.x*128;
  const int tid = threadIdx.x;
  const int wave = tid >> 6, lane = tid & 63;
  const int wr = (wave >> 1) * 64, wc = (wave & 1) * 64;
  const int fr = lane & 15, fq = lane >> 4;      // fragment row/col, k-quad

  f32x4 acc[4][4];
  #pragma unroll
  for (int i=0;i<4;i++)
    #pragma unroll
    for (int j=0;j<4;j++) acc[i][j] = (f32x4){0.f,0.f,0.f,0.f};

  // staging: thread t owns row sr=t>>1, k-halfseg sk=(t&1)*16 (16 f32 -> 16 bf16)
  const int sr = tid >> 1, sk = (tid & 1) * 16;
  const float* arow = Aidx ? (A + (size_t)Aidx[m1+sr]*K) : (A + (size_t)(m1+sr)*K);
  const float* brow = B + (size_t)(n1+sr)*K;

  for (int k0 = 0; k0 < K; k0 += 32){
    float4 a0 = *(const float4*)(arow + k0 + sk);
    float4 a1 = *(const float4*)(arow + k0 + sk + 4);
    float4 a2 = *(const float4*)(arow + k0 + sk + 8);
    float4 a3 = *(const float4*)(arow + k0 + sk + 12);
    float4 b0 = *(const float4*)(brow + k0 + sk);
    float4 b1 = *(const float4*)(brow + k0 + sk + 4);
    float4 b2 = *(const float4*)(brow + k0 + sk + 8);
    float4 b3 = *(const float4*)(brow + k0 + sk + 12);
    bf16x8 ap0, ap1, bp0, bp1;
    ap0[0]=f2bf(a0.x); ap0[1]=f2bf(a0.y); ap0[2]=f2bf(a0.z); ap0[3]=f2bf(a0.w);
    ap0[4]=f2bf(a1.x); ap0[5]=f2bf(a1.y); ap0[6]=f2bf(a1.z); ap0[7]=f2bf(a1.w);
    ap1[0]=f2bf(a2.x); ap1[1]=f2bf(a2.y); ap1[2]=f2bf(a2.z); ap1[3]=f2bf(a2.w);
    ap1[4]=f2bf(a3.x); ap1[5]=f2bf(a3.y); ap1[6]=f2bf(a3.z); ap1[7]=f2bf(a3.w);
    bp0[0]=f2bf(b0.x); bp0[1]=f2bf(b0.y); bp0[2]=f2bf(b0.z); bp0[3]=f2bf(b0.w);
    bp0[4]=f2bf(b1.x); bp0[5]=f2bf(b1.y); bp0[6]=f2bf(b1.z); bp0[7]=f2bf(b1.w);
    bp1[0]=f2bf(b2.x); bp1[1]=f2bf(b2.y); bp1[2]=f2bf(b2.z); bp1[3]=f2bf(b2.w);
    bp1[4]=f2bf(b3.x); bp1[5]=f2bf(b3.y); bp1[6]=f2bf(b3.z); bp1[7]=f2bf(b3.w);

    __syncthreads();   // previous iteration's ds_reads complete before overwrite
    *(bf16x8*)&As[sr][sk]     = ap0;
    *(bf16x8*)&As[sr][sk + 8] = ap1;
    *(bf16x8*)&Bs[sr][sk]     = bp0;
    *(bf16x8*)&Bs[sr][sk + 8] = bp1;
    __syncthreads();

    bf16x8 af[4], bf[4];
    #pragma unroll
    for (int mi=0; mi<4; mi++) af[mi] = *(const bf16x8*)&As[wr + mi*16 + fr][fq*8];
    #pragma unroll
    for (int ni=0; ni<4; ni++) bf[ni] = *(const bf16x8*)&Bs[wc + ni*16 + fr][fq*8];
    #pragma unroll
    for (int mi=0; mi<4; mi++)
      #pragma unroll
      for (int ni=0; ni<4; ni++)
        acc[mi][ni] = __builtin_amdgcn_mfma_f32_16x16x32_bf16(af[mi], bf[ni], acc[mi][ni], 0, 0, 0);
  }

  // epilogue: C/D layout col=lane&15, row=(lane>>4)*4+reg
  #pragma unroll
  for (int ni=0; ni<4; ni++){
    const int col = n1 + wc + ni*16 + fr;
    const float bv = (bias0 ? bias0[col] : 0.f) + (bias1 ? bias1[col] : 0.f);
    #pragma unroll
    for (int mi=0; mi<4; mi++){
      const int row0 = m1 + wr + mi*16 + fq*4;
      #pragma unroll
      for (int j=0; j<4; j++)
        C[(size_t)(row0 + j)*ldc + col] = acc[mi][ni][j] + bv;
    }
  }
}

// ---------------- xp[m,p] = emb(m) . pol_w[p] + pol_b[p] ----------------
__global__ __launch_bounds__(256) void k_xp(const float* __restrict__ enc,
    const int* __restrict__ inputs, const float* __restrict__ pol_w,
    const float* __restrict__ pol_b, float* __restrict__ xp){
  const int m = blockIdx.x;
  const float* x = enc + (size_t)inputs[m]*NINP;
  __shared__ float xs[NINP];
  for (int i=threadIdx.x; i<NINP; i+=256) xs[i] = x[i];
  __syncthreads();
  const int wave = threadIdx.x >> 6, lane = threadIdx.x & 63;
  for (int p = wave; p < NPOL; p += 4){
    const float* w = pol_w + (size_t)p*NINP;
    float s = 0.f;
    for (int k=lane; k<NINP; k+=64) s = fmaf(xs[k], w[k], s);
    #pragma unroll
    for (int off=32; off; off>>=1) s += __shfl_down(s, off);
    if (lane==0) xp[(size_t)m*NPOL + p] = s + pol_b[p];
  }
}

// ---------------- per step, phase 1: gates = xg + h @ w_hh^T ; policy softmax ----------------
__global__ __launch_bounds__(256) void k_step1(
    const float* __restrict__ w_hh, const float* __restrict__ h,
    const float* __restrict__ xg, float* __restrict__ gates,
    const float* __restrict__ mem, const float* __restrict__ conv_w,
    const float* __restrict__ conv_b, const float* __restrict__ xp,
    float* __restrict__ pol, int t){
  const int bid = blockIdx.x, tid = threadIdx.x;
  if (bid < 256){
    __shared__ __align__(16) float hl[32][132];
    __shared__ __align__(16) float wl[16][132];
    const int j0 = bid*16;
    const int b = tid >> 3, jj = tid & 7;
    float acc0 = 0.f, acc1 = 0.f;
    for (int k0=0; k0<NINP; k0+=128){
      #pragma unroll
      for (int i=0;i<16;i++){
        int l = tid + 256*i; int r = l>>7, kk = l&127;
        hl[r][kk] = h[r*NINP + k0 + kk];
      }
      #pragma unroll
      for (int i=0;i<8;i++){
        int l = tid + 256*i; int r = l>>7, kk = l&127;
        wl[r][kk] = w_hh[(size_t)(j0+r)*NINP + k0 + kk];
      }
      __syncthreads();
      #pragma unroll 8
      for (int kk=0; kk<128; kk+=4){
        float4 h4 = *(const float4*)&hl[b][kk];
        float4 wa = *(const float4*)&wl[jj][kk];
        float4 wb = *(const float4*)&wl[jj+8][kk];
        acc0 = fmaf(h4.x,wa.x,acc0); acc0 = fmaf(h4.y,wa.y,acc0);
        acc0 = fmaf(h4.z,wa.z,acc0); acc0 = fmaf(h4.w,wa.w,acc0);
        acc1 = fmaf(h4.x,wb.x,acc1); acc1 = fmaf(h4.y,wb.y,acc1);
        acc1 = fmaf(h4.z,wb.z,acc1); acc1 = fmaf(h4.w,wb.w,acc1);
      }
      __syncthreads();
    }
    const size_t m = (size_t)t*BATCH + b;
    gates[b*NGATE + j0 + jj]     = acc0 + xg[m*NGATE + j0 + jj];
    gates[b*NGATE + j0 + jj + 8] = acc1 + xg[m*NGATE + j0 + jj + 8];
  } else {
    const int b = bid - 256;
    __shared__ float logits[NPOL];
    const int wave = tid >> 6, lane = tid & 63;
    for (int p = wave; p < NPOL; p += 4){
      const int o = p/11, tp = p%11;
      float s = 0.f;
      if (tp < DEPTH){
        const float* mr = mem + b*DEPTH*NINP + tp*NINP;
        for (int n=lane; n<NINP; n+=64) s = fmaf(mr[n], conv_w[o*2*NINP + n*2], s);
      }
      if (tp+1 < DEPTH){
        const float* mr = mem + b*DEPTH*NINP + (tp+1)*NINP;
        for (int n=lane; n<NINP; n+=64) s = fmaf(mr[n], conv_w[o*2*NINP + n*2 + 1], s);
      }
      #pragma unroll
      for (int off=32; off; off>>=1) s += __shfl_down(s, off);
      if (lane==0) logits[p] = s + conv_b[o] + xp[((size_t)t*BATCH + b)*NPOL + p];
    }
    __syncthreads();
    if (tid==0){
      float mx = logits[0];
      for (int p=1;p<NPOL;p++) mx = fmaxf(mx, logits[p]);
      float e[NPOL]; float sum = 0.f;
      for (int p=0;p<NPOL;p++){ e[p] = expf(logits[p]-mx); sum += e[p]; }
      float inv = 1.f/sum;
      for (int p=0;p<NPOL;p++) pol[b*NPOL+p] = e[p]*inv;
    }
  }
}

// ---------------- per step, phase 2: LSTM elementwise + stack memory update ----------------
__global__ __launch_bounds__(256) void k_step2(
    const float* __restrict__ gates, const float* __restrict__ pol,
    float* __restrict__ h, float* __restrict__ c, float* __restrict__ mem,
    float* __restrict__ hs, int t){
  const int gid = blockIdx.x*256 + threadIdx.x;   // 0..32767
  const int b = gid >> 10, n = gid & 1023;
  const float ii = gates[b*NGATE + n];
  const float ff = gates[b*NGATE + NINP + n];
  const float gg = gates[b*NGATE + 2*NINP + n];
  const float oo = gates[b*NGATE + 3*NINP + n];
  float cc = sigf(ff)*c[gid] + sigf(ii)*tanhf(gg);
  float hh = sigf(oo)*tanhf(cc);
  c[gid] = cc; h[gid] = hh;
  hs[((size_t)t*BATCH + b)*NINP + n] = hh;

  float p[NPOL];
  #pragma unroll
  for (int k=0;k<NPOL;k++) p[k] = pol[b*NPOL + k];
  float psum = 0.f;
  #pragma unroll
  for (int k=11;k<22;k++) psum += p[k];
  float m[DEPTH];
  #pragma unroll
  for (int j=0;j<DEPTH;j++) m[j] = mem[b*DEPTH*NINP + j*NINP + n];
  float outv[DEPTH];
  {
    float v = psum*hh;
    #pragma unroll
    for (int j=0;j<DEPTH;j++) v = fmaf(p[j], m[j], v);
    outv[0] = v;
  }
  #pragma unroll
  for (int d=1; d<DEPTH; d++){
    float v = 0.f;
    for (int j=d;   j<DEPTH; j++) v = fmaf(p[j-d],    m[j], v);  // stay: p_stay[j-d]
    for (int j=d-1; j<DEPTH; j++) v = fmaf(p[12+j-d], m[j], v);  // push: p_push[j-d+1]
    outv[d] = v;
  }
  #pragma unroll
  for (int d=0; d<DEPTH; d++) mem[b*DEPTH*NINP + d*NINP + n] = outv[d];
}

// ---------------- tail: hT, cT, memT ----------------
__global__ __launch_bounds__(256) void k_tail(const float* __restrict__ h,
    const float* __restrict__ c, const float* __restrict__ mem, float* __restrict__ out){
  int i = blockIdx.x*256 + threadIdx.x;
  float* o = out + DEC_OFF;
  if (i < BATCH*NINP){ o[i] = h[i]; o[BATCH*NINP + i] = c[i]; }
  if (i < BATCH*DEPTH*NINP){ o[2*BATCH*NINP + i] = mem[i]; }
}

extern "C" void kernel_launch(void* const* d_in, const int* in_sizes, int n_in,
                              void* d_out, int out_size, void* d_ws, size_t ws_size,
                              hipStream_t stream){
  (void)in_sizes; (void)n_in; (void)out_size; (void)ws_size;
  const int*   inputs = (const int*)  d_in[0];
  const float* h0     = (const float*)d_in[1];
  const float* c0     = (const float*)d_in[2];
  const float* m0     = (const float*)d_in[3];
  const float* enc    = (const float*)d_in[4];
  const float* dbias  = (const float*)d_in[5];
  const float* w_ih   = (const float*)d_in[6];
  const float* w_hh   = (const float*)d_in[7];
  const float* b_ih   = (const float*)d_in[8];
  const float* b_hh   = (const float*)d_in[9];
  const float* conv_w = (const float*)d_in[10];
  const float* conv_b = (const float*)d_in[11];
  const float* pol_w  = (const float*)d_in[12];
  const float* pol_b  = (const float*)d_in[13];

  float* out = (float*)d_out;
  float* ws  = (float*)d_ws;
  // ws layout (floats): hs 4194304 | gates 131072 | h 32768 | c 32768 | mem 327680 | xp 90112 | pol 704
  float* hs    = ws;
  float* gates = hs    + 4194304;
  float* hbuf  = gates + 131072;
  float* cbuf  = hbuf  + 32768;
  float* mem   = cbuf  + 32768;
  float* xp    = mem   + 327680;
  float* pol   = xp    + 90112;
  // big scratch xg (SEQ*BATCH x 4096 = 16.7M floats) lives in the decoded region of
  // d_out; it is fully consumed by the scan before the decode GEMM overwrites it.
  float* xg    = out;

  k_init<<<1280, 256, 0, stream>>>(h0, c0, m0, hbuf, cbuf, mem);

  // xg[m,j] = emb(m) . w_ih[j] + b_ih[j] + b_hh[j]   (M=4096, N=4096, K=1024) bf16 MFMA
  dim3 gxg(32, 32);
  k_gemm_bf16<<<gxg, 256, 0, stream>>>(enc, inputs, w_ih, b_ih, b_hh, xg, NINP, NGATE);

  k_xp<<<SEQ*BATCH, 256, 0, stream>>>(enc, inputs, pol_w, pol_b, xp);

  for (int t=0; t<SEQ; ++t){
    k_step1<<<288, 256, 0, stream>>>(w_hh, hbuf, xg, gates, mem, conv_w, conv_b, xp, pol, t);
    k_step2<<<128, 256, 0, stream>>>(gates, pol, hbuf, cbuf, mem, hs, t);
  }

  // decoded = hs @ enc^T + dec_bias   (M=4096, N=32000, K=1024) bf16 MFMA
  dim3 gdec(250, 32);
  k_gemm_bf16<<<gdec, 256, 0, stream>>>(hs, nullptr, enc, dbias, nullptr, out, NINP, NVOCAB);

  k_tail<<<1280, 256, 0, stream>>>(hbuf, cbuf, mem, out);
}